// Round 13
// baseline (329.365 us; speedup 1.0000x reference)
//
#include <hip/hip_runtime.h>
#include <hip/hip_bf16.h>
#include <math.h>

// Problem constants
#define NB 8          // batch
#define NN 1024       // NQ = NK
#define ND 512        // DQ = DK = DV
#define NH 8          // heads
#define NDS 64        // head dim
#define NM 64         // NH * NB
#define LOG_A (-6.93147180559945f)     // -log(1024)
#define SQRT_V 4.75682846001088f       // 512^0.25
#define INV_SQRT_V 0.210224103813429f
#define INV_EPS 10000.0f               // 1/EPS
#define L2E  1.44269504088896f         // log2(e)
#define LN2F 0.693147180559945f
#define IEL2 14426.9504088896f         // INV_EPS * log2(e)
#define SKIP_THR 30.0f                 // 2^-30 < f32 eps relative -> exact skip

#define SPLIT_ELEMS ((size_t)NM * NN * NDS)   // 4,194,304 u16 (8 MB)
#define W_ELEMS     ((size_t)ND * ND)         // 262,144
#define UV_FLOATS   ((size_t)NM * NN)

typedef unsigned short u16;
typedef unsigned int   u32;
typedef __attribute__((ext_vector_type(8))) short bf16x8;   // 8 bf16 = 4 VGPR
typedef __attribute__((ext_vector_type(4))) float f32x4;

#define MFMA16(a,b,c) __builtin_amdgcn_mfma_f32_16x16x32_bf16(a,b,c,0,0,0)

__device__ __forceinline__ u16 f2bf_t(float x) {    // truncating float->bf16
  return (u16)(__float_as_uint(x) >> 16);
}
__device__ __forceinline__ float bf2f(u16 h) {
  return __uint_as_float(((u32)h) << 16);
}
__device__ __forceinline__ float fast_sqrt(float x) {   // v_sqrt_f32
  float r;
  asm("v_sqrt_f32 %0, %1" : "=v"(r) : "v"(x));
  return r;
}
__device__ __forceinline__ float fast_exp2(float x) {   // v_exp_f32 = 2^x
  float r;
  asm("v_exp_f32 %0, %1" : "=v"(r) : "v"(x));
  return r;
}
__device__ __forceinline__ float max3f(float a, float b, float c) {
  float r;
  asm("v_max3_f32 %0, %1, %2, %3" : "=v"(r) : "v"(a), "v"(b), "v"(c));
  return r;
}
// Barrier without full vmcnt drain (neutral vs __syncthreads; kept).
__device__ __forceinline__ void soft_barrier() {
  asm volatile("s_waitcnt lgkmcnt(0)" ::: "memory");
  __builtin_amdgcn_sched_barrier(0);
  __builtin_amdgcn_s_barrier();
  __builtin_amdgcn_sched_barrier(0);
  asm volatile("" ::: "memory");
}
// split 8 f32 into hi/lo bf16x8 planes
__device__ __forceinline__ void split_pack8(float4 a, float4 b,
                                            bf16x8& ho, bf16x8& lo_) {
  float f[8] = {a.x, a.y, a.z, a.w, b.x, b.y, b.z, b.w};
  union { u16 u[8]; bf16x8 v; } H, L;
#pragma unroll
  for (int j = 0; j < 8; ++j) {
    u16 hv = f2bf_t(f[j]);
    H.u[j] = hv;
    L.u[j] = f2bf_t(f[j] - bf2f(hv));
  }
  ho = H.v; lo_ = L.v;
}

// ---------------------------------------------------------------------------
// K0: elementwise f32 -> bf16 hi/lo split (used for the 4 weight matrices).
// ---------------------------------------------------------------------------
__global__ __launch_bounds__(256) void k_split(
    const float* __restrict__ X, u16* __restrict__ hi, u16* __restrict__ lo)
{
  const size_t i = ((size_t)blockIdx.x * 256 + threadIdx.x) * 4;
  float4 v = *(const float4*)&X[i];
  const float* vp = (const float*)&v;
  u16 h[4], l[4];
#pragma unroll
  for (int j = 0; j < 4; ++j) {
    h[j] = f2bf_t(vp[j]);
    l[j] = f2bf_t(vp[j] - bf2f(h[j]));
  }
  uint2 ph, pl;
  ph.x = (u32)h[0] | ((u32)h[1] << 16);
  ph.y = (u32)h[2] | ((u32)h[3] << 16);
  pl.x = (u32)l[0] | ((u32)l[1] << 16);
  pl.y = (u32)l[2] | ((u32)l[3] << 16);
  *(uint2*)&hi[i] = ph;
  *(uint2*)&lo[i] = pl;
}

// ---------------------------------------------------------------------------
// K1: MFMA projection. Reads RAW f32 X, splits in-register during staging
// (no separate Q/K split kernels). Double-buffered LDS + soft barrier.
// ---------------------------------------------------------------------------
__global__ __launch_bounds__(256, 2) void k_proj_mfma(
    const float* __restrict__ Xf,
    const u16* __restrict__ Wh, const u16* __restrict__ Wl,
    const float* __restrict__ bias, u16* __restrict__ oh,
    u16* __restrict__ ol, u16* __restrict__ oT,
    float* __restrict__ nrm, float scale, int mode)
{
  __shared__ __align__(16) u16 Xhs[2][64][72];
  __shared__ __align__(16) u16 Xls[2][64][72];
  __shared__ __align__(16) u16 Whs[2][64][72];
  __shared__ __align__(16) u16 Wls[2][64][72];
  const int t = threadIdx.x;
  const int r0 = blockIdx.x * 64;
  const int h  = blockIdx.y;
  const int c0 = h * 64;
  const int w = t >> 6, l = t & 63;
  const int c = l & 15, kg = l >> 4;
  const int srow = t >> 2;
  const int skoff = (t & 3) * 16;

  const float* gx = &Xf[(size_t)(r0 + srow) * ND + skoff];
  const u16* gwh = &Wh[(size_t)(c0 + srow) * ND + skoff];
  const u16* gwl = &Wl[(size_t)(c0 + srow) * ND + skoff];

  float4 fx0 = *(const float4*)gx;
  float4 fx1 = *(const float4*)(gx + 4);
  float4 fx2 = *(const float4*)(gx + 8);
  float4 fx3 = *(const float4*)(gx + 12);
  bf16x8 rwh0 = *(const bf16x8*)gwh, rwh1 = *(const bf16x8*)(gwh + 8);
  bf16x8 rwl0 = *(const bf16x8*)gwl, rwl1 = *(const bf16x8*)(gwl + 8);

  f32x4 acc[4];
#pragma unroll
  for (int cf = 0; cf < 4; ++cf) acc[cf] = (f32x4){0.f, 0.f, 0.f, 0.f};

  for (int kt = 0; kt < 8; ++kt) {
    const int buf = kt & 1;
    {
      bf16x8 h0, l0, h1, l1;
      split_pack8(fx0, fx1, h0, l0);
      split_pack8(fx2, fx3, h1, l1);
      *(bf16x8*)&Xhs[buf][srow][skoff]     = h0;
      *(bf16x8*)&Xhs[buf][srow][skoff + 8] = h1;
      *(bf16x8*)&Xls[buf][srow][skoff]     = l0;
      *(bf16x8*)&Xls[buf][srow][skoff + 8] = l1;
    }
    *(bf16x8*)&Whs[buf][srow][skoff]     = rwh0;
    *(bf16x8*)&Whs[buf][srow][skoff + 8] = rwh1;
    *(bf16x8*)&Wls[buf][srow][skoff]     = rwl0;
    *(bf16x8*)&Wls[buf][srow][skoff + 8] = rwl1;
    {
      const int nk = ((kt + 1) & 7) * 64;
      fx0 = *(const float4*)(gx + nk);
      fx1 = *(const float4*)(gx + nk + 4);
      fx2 = *(const float4*)(gx + nk + 8);
      fx3 = *(const float4*)(gx + nk + 12);
      rwh0 = *(const bf16x8*)(gwh + nk); rwh1 = *(const bf16x8*)(gwh + nk + 8);
      rwl0 = *(const bf16x8*)(gwl + nk); rwl1 = *(const bf16x8*)(gwl + nk + 8);
    }
    soft_barrier();
#pragma unroll
    for (int ks = 0; ks < 2; ++ks) {
      bf16x8 Ah = *(const bf16x8*)&Xhs[buf][w * 16 + c][ks * 32 + kg * 8];
      bf16x8 Al = *(const bf16x8*)&Xls[buf][w * 16 + c][ks * 32 + kg * 8];
#pragma unroll
      for (int cf = 0; cf < 4; ++cf) {
        bf16x8 Bh = *(const bf16x8*)&Whs[buf][cf * 16 + c][ks * 32 + kg * 8];
        bf16x8 Bl = *(const bf16x8*)&Wls[buf][cf * 16 + c][ks * 32 + kg * 8];
        acc[cf] = MFMA16(Ah, Bh, acc[cf]);
        acc[cf] = MFMA16(Ah, Bl, acc[cf]);
        acc[cf] = MFMA16(Al, Bh, acc[cf]);
      }
    }
  }

  const int bb = r0 >> 10;
  const int n0 = r0 & 1023;
  const size_t mrow = (size_t)(h * NB + bb) * NN;
  if (mode == 0) {
    float ns[4] = {0.f, 0.f, 0.f, 0.f};
#pragma unroll
    for (int cf = 0; cf < 4; ++cf) {
      const int col = c0 + cf * 16 + c;
      const float bv = bias[col];
#pragma unroll
      for (int r = 0; r < 4; ++r) {
        float v = (acc[cf][r] + bv) * scale;
        u16 hv = f2bf_t(v);
        u16 lv = f2bf_t(v - bf2f(hv));
        ns[r] = fmaf(v, v, ns[r]);
        int n = n0 + w * 16 + kg * 4 + r;
        size_t idx = (mrow + n) * NDS + cf * 16 + c;
        oh[idx] = hv;
        ol[idx] = lv;
      }
    }
#pragma unroll
    for (int off = 1; off <= 8; off <<= 1)
#pragma unroll
      for (int r = 0; r < 4; ++r) ns[r] += __shfl_xor(ns[r], off);
    if (c == 0) {
#pragma unroll
      for (int r = 0; r < 4; ++r)
        nrm[mrow + n0 + w * 16 + kg * 4 + r] = ns[r];
    }
  } else {
#pragma unroll
    for (int cf = 0; cf < 4; ++cf) {
      const int d = cf * 16 + c;
      const float bv = bias[c0 + d];
      u16 p0 = f2bf_t((acc[cf][0] + bv) * scale);
      u16 p1 = f2bf_t((acc[cf][1] + bv) * scale);
      u16 p2 = f2bf_t((acc[cf][2] + bv) * scale);
      u16 p3 = f2bf_t((acc[cf][3] + bv) * scale);
      uint2 p;
      p.x = (u32)p0 | ((u32)p1 << 16);
      p.y = (u32)p2 | ((u32)p3 << 16);
      *(uint2*)&oT[((size_t)(h * NB + bb) * NDS + d) * NN + n0 + w * 16 + kg * 4] = p;
    }
  }
}

// ---------------------------------------------------------------------------
// K2: MFMA LSE pass — hi-only cost + wave-uniform exp2-skip. Tiles whose
// per-lane max is > SKIP_THR log2-units below the running max contribute
// < 2^-30 relatively (below f32 eps) -> skipping is bit-exact.
// ---------------------------------------------------------------------------
__global__ __launch_bounds__(512, 4) void k_lse_mfma(
    const u16* __restrict__ Ah_, const u16* __restrict__ Bh_,
    const float* __restrict__ Anrm, const float* __restrict__ Bnrm,
    const float* __restrict__ din, float* __restrict__ dout, int first)
{
  __shared__ __align__(16) float din_s[NN];   // pre-scaled by log2(e)
  __shared__ __align__(16) float y2_s[NN];
  __shared__ __align__(16) u16 Bhs[2][64][72];
  const int t = threadIdx.x;
  const int Lb = blockIdx.x;                  // 512 blocks
  const int xcd = Lb & 7, slot = Lb >> 3;     // slot 0..63
  const int m = xcd + 8 * (slot >> 3);
  const int a0 = (slot & 7) * 128;

  if (first) {
    *(float2*)&din_s[t * 2] = make_float2(0.f, 0.f);
  } else {
    float2 dv = *(const float2*)&din[(size_t)m * NN + t * 2];
    dv.x *= L2E; dv.y *= L2E;
    *(float2*)&din_s[t * 2] = dv;
  }
  *(float2*)&y2_s[t * 2] = *(const float2*)&Bnrm[(size_t)m * NN + t * 2];

  const int w = t >> 6, l = t & 63;
  const int c = l & 15, kg = l >> 4;
  const int arow = a0 + w * 16;
  const size_t mbase = (size_t)m * NN * NDS;

  const u16* pah = &Ah_[mbase + (size_t)(arow + c) * NDS + kg * 8];
  bf16x8 A0h = *(const bf16x8*)pah;
  bf16x8 A1h = *(const bf16x8*)(pah + 32);

  float x2r[4];
#pragma unroll
  for (int r = 0; r < 4; ++r) x2r[r] = Anrm[(size_t)m * NN + arow + kg * 4 + r];
  float M[4], S[4];
#pragma unroll
  for (int r = 0; r < 4; ++r) { M[r] = -3.0e38f; S[r] = 0.f; }

  const int srow = t >> 3;            // 0..63
  const int skoff = (t & 7) * 8;      // one bf16x8 per thread
  const u16* gh = &Bh_[mbase + (size_t)srow * NDS + skoff];
  bf16x8 rh = *(const bf16x8*)gh;
  __syncthreads();   // din_s/y2_s visible

  for (int bt = 0; bt < 16; ++bt) {
    const int b0 = bt * 64;
    const int buf = bt & 1;
    *(bf16x8*)&Bhs[buf][srow][skoff] = rh;
    {   // prefetch next tile (wraps harmlessly at bt=15)
      const size_t noff = (size_t)((bt + 1) & 15) * 4096;
      rh = *(const bf16x8*)(gh + noff);
    }
    soft_barrier();
    f32x4 acc[4];
#pragma unroll
    for (int cf = 0; cf < 4; ++cf) {
      const int bl = cf * 16 + c;
      bf16x8 B0h = *(const bf16x8*)&Bhs[buf][bl][kg * 8];
      bf16x8 B1h = *(const bf16x8*)&Bhs[buf][bl][kg * 8 + 32];
      f32x4 a = {0.f, 0.f, 0.f, 0.f};
      a = MFMA16(A0h, B0h, a);
      a = MFMA16(A1h, B1h, a);
      acc[cf] = a;
    }
    float X[4][4];
#pragma unroll
    for (int cf = 0; cf < 4; ++cf) {
      const int col = b0 + cf * 16 + c;
      const float vb2 = din_s[col];
      const float y2  = y2_s[col];
#pragma unroll
      for (int r = 0; r < 4; ++r) {
        float d2 = fmaf(-2.f, acc[cf][r], x2r[r] + y2);
        float sq = fast_sqrt(fmaxf(d2, 0.f));
        X[cf][r] = fmaf(-IEL2, sq, vb2);
      }
    }
#pragma unroll
    for (int r = 0; r < 4; ++r) {
      float m1 = max3f(X[0][r], X[1][r], X[2][r]);
      float xm = fmaxf(m1, X[3][r]);
      if (__any(xm > M[r] - SKIP_THR)) {
        float nm = fmaxf(xm, M[r]);
        float s4 = fast_exp2(X[0][r] - nm) + fast_exp2(X[1][r] - nm)
                 + fast_exp2(X[2][r] - nm) + fast_exp2(X[3][r] - nm);
        S[r] = fmaf(S[r], fast_exp2(M[r] - nm), s4);
        M[r] = nm;
      }
    }
  }
  // combine across the 16 col-lanes
#pragma unroll
  for (int off = 1; off <= 8; off <<= 1) {
#pragma unroll
    for (int r = 0; r < 4; ++r) {
      float Mo = __shfl_xor(M[r], off);
      float So = __shfl_xor(S[r], off);
      float nm = fmaxf(M[r], Mo);
      S[r] = S[r] * fast_exp2(M[r] - nm) + So * fast_exp2(Mo - nm);
      M[r] = nm;
    }
  }
  if (c == 0) {
#pragma unroll
    for (int r = 0; r < 4; ++r)
      dout[(size_t)m * NN + arow + kg * 4 + r] =
          LOG_A - M[r] * LN2F - __logf(S[r]);
  }
}

// ---------------------------------------------------------------------------
// K3: MFMA PV pass. Hi-only QK^T cost + exp2-skip in the P block; full hi/lo
// q residual. 512 threads / 8 waves; double-buffered LDS; per-wave pT.
// ---------------------------------------------------------------------------
__global__ __launch_bounds__(512, 4) void k_pv_mfma(
    const u16* __restrict__ qh, const u16* __restrict__ ql,
    const u16* __restrict__ kh, const u16* __restrict__ vT,
    const float* __restrict__ qn, const float* __restrict__ kn,
    const float* __restrict__ ue, const float* __restrict__ ve,
    u16* __restrict__ Oh_, u16* __restrict__ Ol_)
{
  __shared__ __align__(16) float ve_s[NN];   // pre-scaled by log2(e)
  __shared__ __align__(16) float y2_s[NN];
  __shared__ __align__(16) u16 Bhs[2][64][72];
  __shared__ __align__(16) u16 Vs[2][64][72];
  __shared__ __align__(16) u16 pT[8][16][40];   // per-wave private
  const int t = threadIdx.x;
  const int Lb = blockIdx.x;                  // 512 blocks
  const int xcd = Lb & 7, slot = Lb >> 3;     // slot 0..63
  const int m = xcd + 8 * (slot >> 3);
  const int a0 = (slot & 7) * 128;
  {
    float2 vv = *(const float2*)&ve[(size_t)m * NN + t * 2];
    vv.x *= L2E; vv.y *= L2E;
    *(float2*)&ve_s[t * 2] = vv;
  }
  *(float2*)&y2_s[t * 2] = *(const float2*)&kn[(size_t)m * NN + t * 2];

  const int w = t >> 6, l = t & 63;
  const int c = l & 15, kg = l >> 4;
  const int arow = a0 + w * 16;
  const size_t mbase = (size_t)m * NN * NDS;

  const u16* pah = &qh[mbase + (size_t)(arow + c) * NDS + kg * 8];
  bf16x8 A0h = *(const bf16x8*)pah;
  bf16x8 A1h = *(const bf16x8*)(pah + 32);

  float x2r[4], uer2[4];
#pragma unroll
  for (int r = 0; r < 4; ++r) {
    x2r[r]  = qn[(size_t)m * NN + arow + kg * 4 + r];
    uer2[r] = ue[(size_t)m * NN + arow + kg * 4 + r] * L2E;
  }
  f32x4 pacc[4];
#pragma unroll
  for (int df = 0; df < 4; ++df) pacc[df] = (f32x4){0.f, 0.f, 0.f, 0.f};

  const int srow = t >> 3;            // 0..63
  const int skoff = (t & 7) * 8;      // one bf16x8 per thread per plane
  const u16* gh = &kh[mbase + (size_t)srow * NDS + skoff];
  const u16* gv = &vT[((size_t)m * NDS + srow) * NN + skoff];
  bf16x8 rh = *(const bf16x8*)gh;
  bf16x8 rv = *(const bf16x8*)gv;
  __syncthreads();   // ve_s/y2_s visible

  for (int bt = 0; bt < 16; ++bt) {
    const int b0 = bt * 64;
    const int buf = bt & 1;
    *(bf16x8*)&Bhs[buf][srow][skoff] = rh;
    *(bf16x8*)&Vs[buf][srow][skoff]  = rv;
    {
      const int nbt = (bt + 1) & 15;
      rh = *(const bf16x8*)(gh + (size_t)nbt * 4096);
      rv = *(const bf16x8*)(gv + (size_t)nbt * 64);
    }
    soft_barrier();
    // two phases: j-half 0 (cf 0..1) then j-half 1 (cf 2..3)
#pragma unroll
    for (int ph = 0; ph < 2; ++ph) {
      f32x4 acc[2];
#pragma unroll
      for (int q = 0; q < 2; ++q) {
        const int cf = ph * 2 + q;
        const int bl = cf * 16 + c;
        bf16x8 B0h = *(const bf16x8*)&Bhs[buf][bl][kg * 8];
        bf16x8 B1h = *(const bf16x8*)&Bhs[buf][bl][kg * 8 + 32];
        f32x4 a = {0.f, 0.f, 0.f, 0.f};
        a = MFMA16(A0h, B0h, a);
        a = MFMA16(A1h, B1h, a);
        acc[q] = a;
      }
#pragma unroll
      for (int q = 0; q < 2; ++q) {
        const int cf = ph * 2 + q;
        const int col = b0 + cf * 16 + c;
        const float ve2 = ve_s[col];
        const float y2  = y2_s[col];
        float arg[4];
#pragma unroll
        for (int r = 0; r < 4; ++r) {
          float d2 = fmaf(-2.f, acc[q][r], x2r[r] + y2);
          float sq = fast_sqrt(fmaxf(d2, 0.f));
          arg[r] = fmaf(-IEL2, sq, uer2[r] + ve2);
        }
        float am = fmaxf(max3f(arg[0], arg[1], arg[2]), arg[3]);
        if (__any(am > -SKIP_THR)) {
#pragma unroll
          for (int r = 0; r < 4; ++r)
            pT[w][kg * 4 + r][q * 16 + c] = f2bf_t(fast_exp2(arg[r]));
        } else {
#pragma unroll
          for (int r = 0; r < 4; ++r)
            pT[w][kg * 4 + r][q * 16 + c] = 0;
        }
      }
      bf16x8 Pa = *(const bf16x8*)&pT[w][c][kg * 8];
#pragma unroll
      for (int df = 0; df < 4; ++df) {
        bf16x8 Vb = *(const bf16x8*)&Vs[buf][df * 16 + c][ph * 32 + kg * 8];
        pacc[df] = MFMA16(Pa, Vb, pacc[df]);
      }
    }
  }
  // epilogue: O = SQRT_V * q + pacc, stored as bf16 hi/lo (truncating)
#pragma unroll
  for (int df = 0; df < 4; ++df) {
#pragma unroll
    for (int r = 0; r < 4; ++r) {
      int row = arow + kg * 4 + r;
      int d = df * 16 + c;
      size_t qi = mbase + (size_t)row * NDS + d;
      float qv = bf2f(qh[qi]) + bf2f(ql[qi]);
      float o  = fmaf(SQRT_V, qv, pacc[df][r]);
      u16 hv = f2bf_t(o);
      Oh_[qi] = hv;
      Ol_[qi] = f2bf_t(o - bf2f(hv));
    }
  }
}

// ---------------------------------------------------------------------------
// K4: MFMA output GEMM. Double-buffered LDS + soft barrier (1/K-step).
// ---------------------------------------------------------------------------
__global__ __launch_bounds__(256, 2) void k_out_mfma(
    const u16* __restrict__ Oh_, const u16* __restrict__ Ol_,
    const u16* __restrict__ Wh, const u16* __restrict__ Wl,
    const float* __restrict__ bo, float* __restrict__ out)
{
  __shared__ __align__(16) u16 Ahs[2][64][72];
  __shared__ __align__(16) u16 Als[2][64][72];
  __shared__ __align__(16) u16 Whs[2][64][72];
  __shared__ __align__(16) u16 Wls[2][64][72];
  const int t = threadIdx.x;
  const int r0 = blockIdx.x * 64;
  const int c0 = blockIdx.y * 64;
  const int bb = r0 >> 10;
  const int n0 = r0 & 1023;
  const int w = t >> 6, l = t & 63;
  const int c = l & 15, kg = l >> 4;
  const int srow = t >> 2;
  const int skoff = (t & 3) * 16;

  f32x4 acc[4];
#pragma unroll
  for (int cf = 0; cf < 4; ++cf) acc[cf] = (f32x4){0.f, 0.f, 0.f, 0.f};

  // prologue: kt = 0
  bf16x8 rah0, rah1, ral0, ral1, rwh0, rwh1, rwl0, rwl1;
  {
    const size_t ob = ((size_t)(0 * NB + bb) * NN + n0 + srow) * NDS;
    const u16* gah = &Oh_[ob + skoff];
    const u16* gal = &Ol_[ob + skoff];
    const u16* gwh = &Wh[(size_t)(c0 + srow) * ND + skoff];
    const u16* gwl = &Wl[(size_t)(c0 + srow) * ND + skoff];
    rah0 = *(const bf16x8*)gah; rah1 = *(const bf16x8*)(gah + 8);
    ral0 = *(const bf16x8*)gal; ral1 = *(const bf16x8*)(gal + 8);
    rwh0 = *(const bf16x8*)gwh; rwh1 = *(const bf16x8*)(gwh + 8);
    rwl0 = *(const bf16x8*)gwl; rwl1 = *(const bf16x8*)(gwl + 8);
  }

  for (int kt = 0; kt < 8; ++kt) {
    const int buf = kt & 1;
    *(bf16x8*)&Ahs[buf][srow][skoff]     = rah0;
    *(bf16x8*)&Ahs[buf][srow][skoff + 8] = rah1;
    *(bf16x8*)&Als[buf][srow][skoff]     = ral0;
    *(bf16x8*)&Als[buf][srow][skoff + 8] = ral1;
    *(bf16x8*)&Whs[buf][srow][skoff]     = rwh0;
    *(bf16x8*)&Whs[buf][srow][skoff + 8] = rwh1;
    *(bf16x8*)&Wls[buf][srow][skoff]     = rwl0;
    *(bf16x8*)&Wls[buf][srow][skoff + 8] = rwl1;
    {
      const int nkt = (kt + 1) & 7;
      const size_t ob = ((size_t)(nkt * NB + bb) * NN + n0 + srow) * NDS;
      const u16* gah = &Oh_[ob + skoff];
      const u16* gal = &Ol_[ob + skoff];
      const u16* gwh = &Wh[(size_t)(c0 + srow) * ND + nkt * 64 + skoff];
      const u16* gwl = &Wl[(size_t)(c0 + srow) * ND + nkt * 64 + skoff];
      rah0 = *(const bf16x8*)gah; rah1 = *(const bf16x8*)(gah + 8);
      ral0 = *(const bf16x8*)gal; ral1 = *(const bf16x8*)(gal + 8);
      rwh0 = *(const bf16x8*)gwh; rwh1 = *(const bf16x8*)(gwh + 8);
      rwl0 = *(const bf16x8*)gwl; rwl1 = *(const bf16x8*)(gwl + 8);
    }
    soft_barrier();
#pragma unroll
    for (int ks = 0; ks < 2; ++ks) {
      bf16x8 Ah = *(const bf16x8*)&Ahs[buf][w * 16 + c][ks * 32 + kg * 8];
      bf16x8 Al = *(const bf16x8*)&Als[buf][w * 16 + c][ks * 32 + kg * 8];
#pragma unroll
      for (int cf = 0; cf < 4; ++cf) {
        bf16x8 Bh = *(const bf16x8*)&Whs[buf][cf * 16 + c][ks * 32 + kg * 8];
        bf16x8 Bl = *(const bf16x8*)&Wls[buf][cf * 16 + c][ks * 32 + kg * 8];
        acc[cf] = MFMA16(Ah, Bh, acc[cf]);
        acc[cf] = MFMA16(Ah, Bl, acc[cf]);
        acc[cf] = MFMA16(Al, Bh, acc[cf]);
      }
    }
  }
#pragma unroll
  for (int cf = 0; cf < 4; ++cf) {
    const int col = c0 + cf * 16 + c;
    const int d = cf * 16 + c;
    const float bv = bo[col];
#pragma unroll
    for (int r = 0; r < 4; ++r) {
      const int n = n0 + w * 16 + kg * 4 + r;
      const size_t oi = ((size_t)(blockIdx.y * NB + bb) * NN + n) * NDS + d;
      float om = bf2f(Oh_[oi]) + bf2f(Ol_[oi]);
      out[(size_t)(r0 + w * 16 + kg * 4 + r) * ND + col] =
          om + fmaxf(acc[cf][r] + bv, 0.f);
    }
  }
}

// ---------------------------------------------------------------------------
extern "C" void kernel_launch(void* const* d_in, const int* in_sizes, int n_in,
                              void* d_out, int out_size, void* d_ws, size_t ws_size,
                              hipStream_t stream) {
  const float* Q  = (const float*)d_in[0];
  const float* K  = (const float*)d_in[1];
  const float* Wq = (const float*)d_in[2];
  const float* bq = (const float*)d_in[3];
  const float* Wk = (const float*)d_in[4];
  const float* bk = (const float*)d_in[5];
  const float* Wv = (const float*)d_in[6];
  const float* bv = (const float*)d_in[7];
  const float* Wo = (const float*)d_in[8];
  const float* bo = (const float*)d_in[9];
  float* out = (float*)d_out;

  const size_t need_bytes =
      7 * SPLIT_ELEMS * sizeof(u16) + 8 * W_ELEMS * sizeof(u16) +
      4 * UV_FLOATS * sizeof(float);
  if (ws_size < need_bytes) return;

  u16* qh = (u16*)d_ws;
  u16* ql = qh + SPLIT_ELEMS;
  u16* kh = ql + SPLIT_ELEMS;
  u16* kl = kh + SPLIT_ELEMS;   // written by proj, unused (hi-only cost)
  u16* vT = kl + SPLIT_ELEMS;
  u16* Oh = vT + SPLIT_ELEMS;
  u16* Ol = Oh + SPLIT_ELEMS;
  u16* wqh = Ol + SPLIT_ELEMS;
  u16* wql = wqh + W_ELEMS;
  u16* wkh = wql + W_ELEMS;
  u16* wkl = wkh + W_ELEMS;
  u16* wvh = wkl + W_ELEMS;
  u16* wvl = wvh + W_ELEMS;
  u16* woh = wvl + W_ELEMS;
  u16* wol = woh + W_ELEMS;
  float* ue = (float*)(wol + W_ELEMS);
  float* ve = ue + UV_FLOATS;
  float* qn = ve + UV_FLOATS;
  float* kn = qn + UV_FLOATS;

  dim3 blk(256);
  k_split<<<dim3(256), blk, 0, stream>>>(Wq, wqh, wql);
  k_split<<<dim3(256), blk, 0, stream>>>(Wk, wkh, wkl);
  k_split<<<dim3(256), blk, 0, stream>>>(Wv, wvh, wvl);
  k_split<<<dim3(256), blk, 0, stream>>>(Wo, woh, wol);
  k_proj_mfma<<<dim3(128, 8), blk, 0, stream>>>(Q, wqh, wql, bq, qh, ql, nullptr, qn, INV_SQRT_V, 0);
  k_proj_mfma<<<dim3(128, 8), blk, 0, stream>>>(K, wkh, wkl, bk, kh, kl, nullptr, kn, INV_SQRT_V, 0);
  k_proj_mfma<<<dim3(128, 8), blk, 0, stream>>>(K, wvh, wvl, bv, nullptr, nullptr, vT, nullptr, 1.0f, 1);
  for (int it = 0; it < 3; ++it) {
    k_lse_mfma<<<dim3(512), dim3(512), 0, stream>>>(qh, kh, qn, kn, ve, ue, it == 0 ? 1 : 0);
    k_lse_mfma<<<dim3(512), dim3(512), 0, stream>>>(kh, qh, kn, qn, ue, ve, 0);
  }
  k_pv_mfma<<<dim3(512), dim3(512), 0, stream>>>(qh, ql, kh, vT, qn, kn, ue, ve, Oh, Ol);
  k_out_mfma<<<dim3(128, 8), blk, 0, stream>>>(Oh, Ol, woh, wol, bo, out);
}

// Round 14
// 311.772 us; speedup vs baseline: 1.0564x; 1.0564x over previous
//
#include <hip/hip_runtime.h>
#include <hip/hip_bf16.h>
#include <math.h>

// Problem constants
#define NB 8          // batch
#define NN 1024       // NQ = NK
#define ND 512        // DQ = DK = DV
#define NH 8          // heads
#define NDS 64        // head dim
#define NM 64         // NH * NB
#define LOG_A (-6.93147180559945f)     // -log(1024)
#define SQRT_V 4.75682846001088f       // 512^0.25
#define INV_SQRT_V 0.210224103813429f
#define INV_EPS 10000.0f               // 1/EPS
#define L2E  1.44269504088896f         // log2(e)
#define LN2F 0.693147180559945f
#define IEL2 14426.9504088896f         // INV_EPS * log2(e)

#define SPLIT_ELEMS ((size_t)NM * NN * NDS)   // 4,194,304 u16 (8 MB)
#define W_ELEMS     ((size_t)ND * ND)         // 262,144
#define UV_FLOATS   ((size_t)NM * NN)

typedef unsigned short u16;
typedef unsigned int   u32;
typedef __attribute__((ext_vector_type(8))) short bf16x8;   // 8 bf16 = 4 VGPR
typedef __attribute__((ext_vector_type(4))) float f32x4;

#define MFMA16(a,b,c) __builtin_amdgcn_mfma_f32_16x16x32_bf16(a,b,c,0,0,0)

__device__ __forceinline__ u16 f2bf_t(float x) {    // truncating float->bf16
  return (u16)(__float_as_uint(x) >> 16);
}
__device__ __forceinline__ float bf2f(u16 h) {
  return __uint_as_float(((u32)h) << 16);
}
__device__ __forceinline__ float fast_sqrt(float x) {   // v_sqrt_f32
  float r;
  asm("v_sqrt_f32 %0, %1" : "=v"(r) : "v"(x));
  return r;
}
__device__ __forceinline__ float fast_exp2(float x) {   // v_exp_f32 = 2^x
  float r;
  asm("v_exp_f32 %0, %1" : "=v"(r) : "v"(x));
  return r;
}
__device__ __forceinline__ float max3f(float a, float b, float c) {
  float r;
  asm("v_max3_f32 %0, %1, %2, %3" : "=v"(r) : "v"(a), "v"(b), "v"(c));
  return r;
}
// Barrier that makes LDS writes visible without draining in-flight global
// loads (neutral vs __syncthreads in round-10 A/B, kept).
__device__ __forceinline__ void soft_barrier() {
  asm volatile("s_waitcnt lgkmcnt(0)" ::: "memory");
  __builtin_amdgcn_sched_barrier(0);
  __builtin_amdgcn_s_barrier();
  __builtin_amdgcn_sched_barrier(0);
  asm volatile("" ::: "memory");
}

// ---------------------------------------------------------------------------
// K0: elementwise f32 -> bf16 hi/lo split (truncating).
// ---------------------------------------------------------------------------
__global__ __launch_bounds__(256) void k_split(
    const float* __restrict__ X, u16* __restrict__ hi, u16* __restrict__ lo)
{
  const size_t i = ((size_t)blockIdx.x * 256 + threadIdx.x) * 4;
  float4 v = *(const float4*)&X[i];
  const float* vp = (const float*)&v;
  u16 h[4], l[4];
#pragma unroll
  for (int j = 0; j < 4; ++j) {
    h[j] = f2bf_t(vp[j]);
    l[j] = f2bf_t(vp[j] - bf2f(h[j]));
  }
  uint2 ph, pl;
  ph.x = (u32)h[0] | ((u32)h[1] << 16);
  ph.y = (u32)h[2] | ((u32)h[3] << 16);
  pl.x = (u32)l[0] | ((u32)l[1] << 16);
  pl.y = (u32)l[2] | ((u32)l[3] << 16);
  *(uint2*)&hi[i] = ph;
  *(uint2*)&lo[i] = pl;
}

// ---------------------------------------------------------------------------
// K1: MFMA projection. Double-buffered LDS + soft barrier (1/K-step).
// mode 0: hi/lo split out + norms. mode 1: transposed bf16 out.
// mode 2: hi-only out + norms (K-projection; lo plane unused downstream).
// ---------------------------------------------------------------------------
__global__ __launch_bounds__(256, 2) void k_proj_mfma(
    const u16* __restrict__ Xh, const u16* __restrict__ Xl,
    const u16* __restrict__ Wh, const u16* __restrict__ Wl,
    const float* __restrict__ bias, u16* __restrict__ oh,
    u16* __restrict__ ol, u16* __restrict__ oT,
    float* __restrict__ nrm, float scale, int mode)
{
  __shared__ __align__(16) u16 Xhs[2][64][72];
  __shared__ __align__(16) u16 Xls[2][64][72];
  __shared__ __align__(16) u16 Whs[2][64][72];
  __shared__ __align__(16) u16 Wls[2][64][72];
  const int t = threadIdx.x;
  const int r0 = blockIdx.x * 64;
  const int h  = blockIdx.y;
  const int c0 = h * 64;
  const int w = t >> 6, l = t & 63;
  const int c = l & 15, kg = l >> 4;
  const int srow = t >> 2;
  const int skoff = (t & 3) * 16;

  const u16* gxh = &Xh[(size_t)(r0 + srow) * ND + skoff];
  const u16* gxl = &Xl[(size_t)(r0 + srow) * ND + skoff];
  const u16* gwh = &Wh[(size_t)(c0 + srow) * ND + skoff];
  const u16* gwl = &Wl[(size_t)(c0 + srow) * ND + skoff];

  bf16x8 rxh0 = *(const bf16x8*)gxh, rxh1 = *(const bf16x8*)(gxh + 8);
  bf16x8 rxl0 = *(const bf16x8*)gxl, rxl1 = *(const bf16x8*)(gxl + 8);
  bf16x8 rwh0 = *(const bf16x8*)gwh, rwh1 = *(const bf16x8*)(gwh + 8);
  bf16x8 rwl0 = *(const bf16x8*)gwl, rwl1 = *(const bf16x8*)(gwl + 8);

  f32x4 acc[4];
#pragma unroll
  for (int cf = 0; cf < 4; ++cf) acc[cf] = (f32x4){0.f, 0.f, 0.f, 0.f};

  for (int kt = 0; kt < 8; ++kt) {
    const int buf = kt & 1;
    *(bf16x8*)&Xhs[buf][srow][skoff]     = rxh0;
    *(bf16x8*)&Xhs[buf][srow][skoff + 8] = rxh1;
    *(bf16x8*)&Xls[buf][srow][skoff]     = rxl0;
    *(bf16x8*)&Xls[buf][srow][skoff + 8] = rxl1;
    *(bf16x8*)&Whs[buf][srow][skoff]     = rwh0;
    *(bf16x8*)&Whs[buf][srow][skoff + 8] = rwh1;
    *(bf16x8*)&Wls[buf][srow][skoff]     = rwl0;
    *(bf16x8*)&Wls[buf][srow][skoff + 8] = rwl1;
    {
      const int nk = ((kt + 1) & 7) * 64;
      rxh0 = *(const bf16x8*)(gxh + nk); rxh1 = *(const bf16x8*)(gxh + nk + 8);
      rxl0 = *(const bf16x8*)(gxl + nk); rxl1 = *(const bf16x8*)(gxl + nk + 8);
      rwh0 = *(const bf16x8*)(gwh + nk); rwh1 = *(const bf16x8*)(gwh + nk + 8);
      rwl0 = *(const bf16x8*)(gwl + nk); rwl1 = *(const bf16x8*)(gwl + nk + 8);
    }
    soft_barrier();
#pragma unroll
    for (int ks = 0; ks < 2; ++ks) {
      bf16x8 Ah = *(const bf16x8*)&Xhs[buf][w * 16 + c][ks * 32 + kg * 8];
      bf16x8 Al = *(const bf16x8*)&Xls[buf][w * 16 + c][ks * 32 + kg * 8];
#pragma unroll
      for (int cf = 0; cf < 4; ++cf) {
        bf16x8 Bh = *(const bf16x8*)&Whs[buf][cf * 16 + c][ks * 32 + kg * 8];
        bf16x8 Bl = *(const bf16x8*)&Wls[buf][cf * 16 + c][ks * 32 + kg * 8];
        acc[cf] = MFMA16(Ah, Bh, acc[cf]);
        acc[cf] = MFMA16(Ah, Bl, acc[cf]);
        acc[cf] = MFMA16(Al, Bh, acc[cf]);
      }
    }
  }

  const int bb = r0 >> 10;
  const int n0 = r0 & 1023;
  const size_t mrow = (size_t)(h * NB + bb) * NN;
  if (mode != 1) {
    float ns[4] = {0.f, 0.f, 0.f, 0.f};
#pragma unroll
    for (int cf = 0; cf < 4; ++cf) {
      const int col = c0 + cf * 16 + c;
      const float bv = bias[col];
#pragma unroll
      for (int r = 0; r < 4; ++r) {
        float v = (acc[cf][r] + bv) * scale;
        u16 hv = f2bf_t(v);
        ns[r] = fmaf(v, v, ns[r]);
        int n = n0 + w * 16 + kg * 4 + r;
        size_t idx = (mrow + n) * NDS + cf * 16 + c;
        oh[idx] = hv;
        if (mode == 0) ol[idx] = f2bf_t(v - bf2f(hv));
      }
    }
#pragma unroll
    for (int off = 1; off <= 8; off <<= 1)
#pragma unroll
      for (int r = 0; r < 4; ++r) ns[r] += __shfl_xor(ns[r], off);
    if (c == 0) {
#pragma unroll
      for (int r = 0; r < 4; ++r)
        nrm[mrow + n0 + w * 16 + kg * 4 + r] = ns[r];
    }
  } else {
#pragma unroll
    for (int cf = 0; cf < 4; ++cf) {
      const int d = cf * 16 + c;
      const float bv = bias[c0 + d];
      u16 p0 = f2bf_t((acc[cf][0] + bv) * scale);
      u16 p1 = f2bf_t((acc[cf][1] + bv) * scale);
      u16 p2 = f2bf_t((acc[cf][2] + bv) * scale);
      u16 p3 = f2bf_t((acc[cf][3] + bv) * scale);
      uint2 p;
      p.x = (u32)p0 | ((u32)p1 << 16);
      p.y = (u32)p2 | ((u32)p3 << 16);
      *(uint2*)&oT[((size_t)(h * NB + bb) * NDS + d) * NN + n0 + w * 16 + kg * 4] = p;
    }
  }
}

// ---------------------------------------------------------------------------
// K2: MFMA LSE pass — hi-only cost (2 MFMAs per fragment), consistent across
// all passes so the duals self-normalize the perturbed metric. 512 threads /
// 8 waves; double-buffered single-plane LDS, one soft barrier per tile.
// ---------------------------------------------------------------------------
__global__ __launch_bounds__(512, 4) void k_lse_mfma(
    const u16* __restrict__ Ah_, const u16* __restrict__ Bh_,
    const float* __restrict__ Anrm, const float* __restrict__ Bnrm,
    const float* __restrict__ din, float* __restrict__ dout, int first)
{
  __shared__ __align__(16) float din_s[NN];   // pre-scaled by log2(e)
  __shared__ __align__(16) float y2_s[NN];
  __shared__ __align__(16) u16 Bhs[2][64][72];
  const int t = threadIdx.x;
  const int Lb = blockIdx.x;                  // 512 blocks
  const int xcd = Lb & 7, slot = Lb >> 3;     // slot 0..63
  const int m = xcd + 8 * (slot >> 3);
  const int a0 = (slot & 7) * 128;

  if (first) {
    *(float2*)&din_s[t * 2] = make_float2(0.f, 0.f);
  } else {
    float2 dv = *(const float2*)&din[(size_t)m * NN + t * 2];
    dv.x *= L2E; dv.y *= L2E;
    *(float2*)&din_s[t * 2] = dv;
  }
  *(float2*)&y2_s[t * 2] = *(const float2*)&Bnrm[(size_t)m * NN + t * 2];

  const int w = t >> 6, l = t & 63;
  const int c = l & 15, kg = l >> 4;
  const int arow = a0 + w * 16;
  const size_t mbase = (size_t)m * NN * NDS;

  const u16* pah = &Ah_[mbase + (size_t)(arow + c) * NDS + kg * 8];
  bf16x8 A0h = *(const bf16x8*)pah;
  bf16x8 A1h = *(const bf16x8*)(pah + 32);

  float x2r[4];
#pragma unroll
  for (int r = 0; r < 4; ++r) x2r[r] = Anrm[(size_t)m * NN + arow + kg * 4 + r];
  float M[4], S[4];
#pragma unroll
  for (int r = 0; r < 4; ++r) { M[r] = -3.0e38f; S[r] = 0.f; }

  const int srow = t >> 3;            // 0..63
  const int skoff = (t & 7) * 8;      // one bf16x8 per thread
  const u16* gh = &Bh_[mbase + (size_t)srow * NDS + skoff];
  bf16x8 rh = *(const bf16x8*)gh;
  __syncthreads();   // din_s/y2_s visible

  for (int bt = 0; bt < 16; ++bt) {
    const int b0 = bt * 64;
    const int buf = bt & 1;
    *(bf16x8*)&Bhs[buf][srow][skoff] = rh;
    {   // prefetch next tile (wraps harmlessly at bt=15)
      const size_t noff = (size_t)((bt + 1) & 15) * 4096;
      rh = *(const bf16x8*)(gh + noff);
    }
    soft_barrier();
    f32x4 acc[4];
#pragma unroll
    for (int cf = 0; cf < 4; ++cf) {
      const int bl = cf * 16 + c;
      bf16x8 B0h = *(const bf16x8*)&Bhs[buf][bl][kg * 8];
      bf16x8 B1h = *(const bf16x8*)&Bhs[buf][bl][kg * 8 + 32];
      f32x4 a = {0.f, 0.f, 0.f, 0.f};
      a = MFMA16(A0h, B0h, a);
      a = MFMA16(A1h, B1h, a);
      acc[cf] = a;
    }
    float X[4][4];
#pragma unroll
    for (int cf = 0; cf < 4; ++cf) {
      const int col = b0 + cf * 16 + c;
      const float vb2 = din_s[col];
      const float y2  = y2_s[col];
#pragma unroll
      for (int r = 0; r < 4; ++r) {
        float d2 = fmaf(-2.f, acc[cf][r], x2r[r] + y2);
        float sq = fast_sqrt(fmaxf(d2, 0.f));
        X[cf][r] = fmaf(-IEL2, sq, vb2);
      }
    }
#pragma unroll
    for (int r = 0; r < 4; ++r) {
      float m1 = max3f(X[0][r], X[1][r], X[2][r]);
      float nm = max3f(m1, X[3][r], M[r]);
      float s4 = fast_exp2(X[0][r] - nm) + fast_exp2(X[1][r] - nm)
               + fast_exp2(X[2][r] - nm) + fast_exp2(X[3][r] - nm);
      S[r] = fmaf(S[r], fast_exp2(M[r] - nm), s4);
      M[r] = nm;
    }
  }
  // combine across the 16 col-lanes
#pragma unroll
  for (int off = 1; off <= 8; off <<= 1) {
#pragma unroll
    for (int r = 0; r < 4; ++r) {
      float Mo = __shfl_xor(M[r], off);
      float So = __shfl_xor(S[r], off);
      float nm = fmaxf(M[r], Mo);
      S[r] = S[r] * fast_exp2(M[r] - nm) + So * fast_exp2(Mo - nm);
      M[r] = nm;
    }
  }
  if (c == 0) {
#pragma unroll
    for (int r = 0; r < 4; ++r)
      dout[(size_t)m * NN + arow + kg * 4 + r] =
          LOG_A - M[r] * LN2F - __logf(S[r]);
  }
}

// ---------------------------------------------------------------------------
// K3: MFMA PV pass. Hi-only QK^T cost (consistent with LSE passes); full
// hi/lo q residual in the epilogue. 512 threads / 8 waves; double-buffered
// LDS, one soft barrier per tile; per-wave private pT; two-phase PV.
// ---------------------------------------------------------------------------
__global__ __launch_bounds__(512, 4) void k_pv_mfma(
    const u16* __restrict__ qh, const u16* __restrict__ ql,
    const u16* __restrict__ kh, const u16* __restrict__ vT,
    const float* __restrict__ qn, const float* __restrict__ kn,
    const float* __restrict__ ue, const float* __restrict__ ve,
    u16* __restrict__ Oh_, u16* __restrict__ Ol_)
{
  __shared__ __align__(16) float ve_s[NN];   // pre-scaled by log2(e)
  __shared__ __align__(16) float y2_s[NN];
  __shared__ __align__(16) u16 Bhs[2][64][72];
  __shared__ __align__(16) u16 Vs[2][64][72];
  __shared__ __align__(16) u16 pT[8][16][40];   // per-wave private
  const int t = threadIdx.x;
  const int Lb = blockIdx.x;                  // 512 blocks
  const int xcd = Lb & 7, slot = Lb >> 3;     // slot 0..63
  const int m = xcd + 8 * (slot >> 3);
  const int a0 = (slot & 7) * 128;
  {
    float2 vv = *(const float2*)&ve[(size_t)m * NN + t * 2];
    vv.x *= L2E; vv.y *= L2E;
    *(float2*)&ve_s[t * 2] = vv;
  }
  *(float2*)&y2_s[t * 2] = *(const float2*)&kn[(size_t)m * NN + t * 2];

  const int w = t >> 6, l = t & 63;
  const int c = l & 15, kg = l >> 4;
  const int arow = a0 + w * 16;
  const size_t mbase = (size_t)m * NN * NDS;

  const u16* pah = &qh[mbase + (size_t)(arow + c) * NDS + kg * 8];
  bf16x8 A0h = *(const bf16x8*)pah;
  bf16x8 A1h = *(const bf16x8*)(pah + 32);

  float x2r[4], uer2[4];
#pragma unroll
  for (int r = 0; r < 4; ++r) {
    x2r[r]  = qn[(size_t)m * NN + arow + kg * 4 + r];
    uer2[r] = ue[(size_t)m * NN + arow + kg * 4 + r] * L2E;
  }
  f32x4 pacc[4];
#pragma unroll
  for (int df = 0; df < 4; ++df) pacc[df] = (f32x4){0.f, 0.f, 0.f, 0.f};

  const int srow = t >> 3;            // 0..63
  const int skoff = (t & 7) * 8;      // one bf16x8 per thread per plane
  const u16* gh = &kh[mbase + (size_t)srow * NDS + skoff];
  const u16* gv = &vT[((size_t)m * NDS + srow) * NN + skoff];
  bf16x8 rh = *(const bf16x8*)gh;
  bf16x8 rv = *(const bf16x8*)gv;
  __syncthreads();   // ve_s/y2_s visible

  for (int bt = 0; bt < 16; ++bt) {
    const int b0 = bt * 64;
    const int buf = bt & 1;
    *(bf16x8*)&Bhs[buf][srow][skoff] = rh;
    *(bf16x8*)&Vs[buf][srow][skoff]  = rv;
    {
      const int nbt = (bt + 1) & 15;
      rh = *(const bf16x8*)(gh + (size_t)nbt * 4096);
      rv = *(const bf16x8*)(gv + (size_t)nbt * 64);
    }
    soft_barrier();
    // two phases: j-half 0 (cf 0..1) then j-half 1 (cf 2..3)
#pragma unroll
    for (int ph = 0; ph < 2; ++ph) {
      f32x4 acc[2];
#pragma unroll
      for (int q = 0; q < 2; ++q) {
        const int cf = ph * 2 + q;
        const int bl = cf * 16 + c;
        bf16x8 B0h = *(const bf16x8*)&Bhs[buf][bl][kg * 8];
        bf16x8 B1h = *(const bf16x8*)&Bhs[buf][bl][kg * 8 + 32];
        f32x4 a = {0.f, 0.f, 0.f, 0.f};
        a = MFMA16(A0h, B0h, a);
        a = MFMA16(A1h, B1h, a);
        acc[q] = a;
      }
#pragma unroll
      for (int q = 0; q < 2; ++q) {
        const int cf = ph * 2 + q;
        const int col = b0 + cf * 16 + c;
        const float ve2 = ve_s[col];
        const float y2  = y2_s[col];
#pragma unroll
        for (int r = 0; r < 4; ++r) {
          float d2 = fmaf(-2.f, acc[q][r], x2r[r] + y2);
          float sq = fast_sqrt(fmaxf(d2, 0.f));
          float p  = fast_exp2(fmaf(-IEL2, sq, uer2[r] + ve2));
          pT[w][kg * 4 + r][q * 16 + c] = f2bf_t(p);
        }
      }
      bf16x8 Pa = *(const bf16x8*)&pT[w][c][kg * 8];
#pragma unroll
      for (int df = 0; df < 4; ++df) {
        bf16x8 Vb = *(const bf16x8*)&Vs[buf][df * 16 + c][ph * 32 + kg * 8];
        pacc[df] = MFMA16(Pa, Vb, pacc[df]);
      }
    }
  }
  // epilogue: O = SQRT_V * q + pacc, stored as bf16 hi/lo (truncating)
#pragma unroll
  for (int df = 0; df < 4; ++df) {
#pragma unroll
    for (int r = 0; r < 4; ++r) {
      int row = arow + kg * 4 + r;
      int d = df * 16 + c;
      size_t qi = mbase + (size_t)row * NDS + d;
      float qv = bf2f(qh[qi]) + bf2f(ql[qi]);
      float o  = fmaf(SQRT_V, qv, pacc[df][r]);
      u16 hv = f2bf_t(o);
      Oh_[qi] = hv;
      Ol_[qi] = f2bf_t(o - bf2f(hv));
    }
  }
}

// ---------------------------------------------------------------------------
// K4: MFMA output GEMM. Double-buffered LDS + soft barrier (1/K-step).
// ---------------------------------------------------------------------------
__global__ __launch_bounds__(256, 2) void k_out_mfma(
    const u16* __restrict__ Oh_, const u16* __restrict__ Ol_,
    const u16* __restrict__ Wh, const u16* __restrict__ Wl,
    const float* __restrict__ bo, float* __restrict__ out)
{
  __shared__ __align__(16) u16 Ahs[2][64][72];
  __shared__ __align__(16) u16 Als[2][64][72];
  __shared__ __align__(16) u16 Whs[2][64][72];
  __shared__ __align__(16) u16 Wls[2][64][72];
  const int t = threadIdx.x;
  const int r0 = blockIdx.x * 64;
  const int c0 = blockIdx.y * 64;
  const int bb = r0 >> 10;
  const int n0 = r0 & 1023;
  const int w = t >> 6, l = t & 63;
  const int c = l & 15, kg = l >> 4;
  const int srow = t >> 2;
  const int skoff = (t & 3) * 16;

  f32x4 acc[4];
#pragma unroll
  for (int cf = 0; cf < 4; ++cf) acc[cf] = (f32x4){0.f, 0.f, 0.f, 0.f};

  // prologue: kt = 0
  bf16x8 rah0, rah1, ral0, ral1, rwh0, rwh1, rwl0, rwl1;
  {
    const size_t ob = ((size_t)(0 * NB + bb) * NN + n0 + srow) * NDS;
    const u16* gah = &Oh_[ob + skoff];
    const u16* gal = &Ol_[ob + skoff];
    const u16* gwh = &Wh[(size_t)(c0 + srow) * ND + skoff];
    const u16* gwl = &Wl[(size_t)(c0 + srow) * ND + skoff];
    rah0 = *(const bf16x8*)gah; rah1 = *(const bf16x8*)(gah + 8);
    ral0 = *(const bf16x8*)gal; ral1 = *(const bf16x8*)(gal + 8);
    rwh0 = *(const bf16x8*)gwh; rwh1 = *(const bf16x8*)(gwh + 8);
    rwl0 = *(const bf16x8*)gwl; rwl1 = *(const bf16x8*)(gwl + 8);
  }

  for (int kt = 0; kt < 8; ++kt) {
    const int buf = kt & 1;
    *(bf16x8*)&Ahs[buf][srow][skoff]     = rah0;
    *(bf16x8*)&Ahs[buf][srow][skoff + 8] = rah1;
    *(bf16x8*)&Als[buf][srow][skoff]     = ral0;
    *(bf16x8*)&Als[buf][srow][skoff + 8] = ral1;
    *(bf16x8*)&Whs[buf][srow][skoff]     = rwh0;
    *(bf16x8*)&Whs[buf][srow][skoff + 8] = rwh1;
    *(bf16x8*)&Wls[buf][srow][skoff]     = rwl0;
    *(bf16x8*)&Wls[buf][srow][skoff + 8] = rwl1;
    {
      const int nkt = (kt + 1) & 7;
      const size_t ob = ((size_t)(nkt * NB + bb) * NN + n0 + srow) * NDS;
      const u16* gah = &Oh_[ob + skoff];
      const u16* gal = &Ol_[ob + skoff];
      const u16* gwh = &Wh[(size_t)(c0 + srow) * ND + nkt * 64 + skoff];
      const u16* gwl = &Wl[(size_t)(c0 + srow) * ND + nkt * 64 + skoff];
      rah0 = *(const bf16x8*)gah; rah1 = *(const bf16x8*)(gah + 8);
      ral0 = *(const bf16x8*)gal; ral1 = *(const bf16x8*)(gal + 8);
      rwh0 = *(const bf16x8*)gwh; rwh1 = *(const bf16x8*)(gwh + 8);
      rwl0 = *(const bf16x8*)gwl; rwl1 = *(const bf16x8*)(gwl + 8);
    }
    soft_barrier();
#pragma unroll
    for (int ks = 0; ks < 2; ++ks) {
      bf16x8 Ah = *(const bf16x8*)&Ahs[buf][w * 16 + c][ks * 32 + kg * 8];
      bf16x8 Al = *(const bf16x8*)&Als[buf][w * 16 + c][ks * 32 + kg * 8];
#pragma unroll
      for (int cf = 0; cf < 4; ++cf) {
        bf16x8 Bh = *(const bf16x8*)&Whs[buf][cf * 16 + c][ks * 32 + kg * 8];
        bf16x8 Bl = *(const bf16x8*)&Wls[buf][cf * 16 + c][ks * 32 + kg * 8];
        acc[cf] = MFMA16(Ah, Bh, acc[cf]);
        acc[cf] = MFMA16(Ah, Bl, acc[cf]);
        acc[cf] = MFMA16(Al, Bh, acc[cf]);
      }
    }
  }
#pragma unroll
  for (int cf = 0; cf < 4; ++cf) {
    const int col = c0 + cf * 16 + c;
    const int d = cf * 16 + c;
    const float bv = bo[col];
#pragma unroll
    for (int r = 0; r < 4; ++r) {
      const int n = n0 + w * 16 + kg * 4 + r;
      const size_t oi = ((size_t)(blockIdx.y * NB + bb) * NN + n) * NDS + d;
      float om = bf2f(Oh_[oi]) + bf2f(Ol_[oi]);
      out[(size_t)(r0 + w * 16 + kg * 4 + r) * ND + col] =
          om + fmaxf(acc[cf][r] + bv, 0.f);
    }
  }
}

// ---------------------------------------------------------------------------
extern "C" void kernel_launch(void* const* d_in, const int* in_sizes, int n_in,
                              void* d_out, int out_size, void* d_ws, size_t ws_size,
                              hipStream_t stream) {
  const float* Q  = (const float*)d_in[0];
  const float* K  = (const float*)d_in[1];
  const float* Wq = (const float*)d_in[2];
  const float* bq = (const float*)d_in[3];
  const float* Wk = (const float*)d_in[4];
  const float* bk = (const float*)d_in[5];
  const float* Wv = (const float*)d_in[6];
  const float* bv = (const float*)d_in[7];
  const float* Wo = (const float*)d_in[8];
  const float* bo = (const float*)d_in[9];
  float* out = (float*)d_out;

  const size_t need_bytes =
      7 * SPLIT_ELEMS * sizeof(u16) + 8 * W_ELEMS * sizeof(u16) +
      4 * UV_FLOATS * sizeof(float);
  if (ws_size < need_bytes) return;

  u16* qh = (u16*)d_ws;
  u16* ql = qh + SPLIT_ELEMS;
  u16* kh = ql + SPLIT_ELEMS;
  u16* kl = kh + SPLIT_ELEMS;   // unused (hi-only cost; K-proj uses mode 2)
  u16* vT = kl + SPLIT_ELEMS;
  u16* Oh = vT + SPLIT_ELEMS;   // phase 1-2: raw Q split; phase 3+: O hi
  u16* Ol = Oh + SPLIT_ELEMS;
  u16* wqh = Ol + SPLIT_ELEMS;
  u16* wql = wqh + W_ELEMS;
  u16* wkh = wql + W_ELEMS;
  u16* wkl = wkh + W_ELEMS;
  u16* wvh = wkl + W_ELEMS;
  u16* wvl = wvh + W_ELEMS;
  u16* woh = wvl + W_ELEMS;
  u16* wol = woh + W_ELEMS;
  float* ue = (float*)(wol + W_ELEMS);
  float* ve = ue + UV_FLOATS;
  float* qn = ve + UV_FLOATS;
  float* kn = qn + UV_FLOATS;

  u16* Qrh = Oh;                  // aliased raw input splits
  u16* Qrl = Ol;
  u16* Krh = (u16*)d_out;         // d_out fully overwritten at end
  u16* Krl = Krh + SPLIT_ELEMS;

  dim3 blk(256);
  k_split<<<dim3(4096), blk, 0, stream>>>(Q, Qrh, Qrl);
  k_split<<<dim3(4096), blk, 0, stream>>>(K, Krh, Krl);
  k_split<<<dim3(256), blk, 0, stream>>>(Wq, wqh, wql);
  k_split<<<dim3(256), blk, 0, stream>>>(Wk, wkh, wkl);
  k_split<<<dim3(256), blk, 0, stream>>>(Wv, wvh, wvl);
  k_split<<<dim3(256), blk, 0, stream>>>(Wo, woh, wol);
  k_proj_mfma<<<dim3(128, 8), blk, 0, stream>>>(Qrh, Qrl, wqh, wql, bq, qh, ql, nullptr, qn, INV_SQRT_V, 0);
  k_proj_mfma<<<dim3(128, 8), blk, 0, stream>>>(Krh, Krl, wkh, wkl, bk, kh, nullptr, nullptr, kn, INV_SQRT_V, 2);
  k_proj_mfma<<<dim3(128, 8), blk, 0, stream>>>(Krh, Krl, wvh, wvl, bv, nullptr, nullptr, vT, nullptr, 1.0f, 1);
  for (int it = 0; it < 3; ++it) {
    k_lse_mfma<<<dim3(512), dim3(512), 0, stream>>>(qh, kh, qn, kn, ve, ue, it == 0 ? 1 : 0);
    k_lse_mfma<<<dim3(512), dim3(512), 0, stream>>>(kh, qh, kn, qn, ue, ve, 0);
  }
  k_pv_mfma<<<dim3(512), dim3(512), 0, stream>>>(qh, ql, kh, vT, qn, kn, ue, ve, Oh, Ol);
  k_out_mfma<<<dim3(128, 8), blk, 0, stream>>>(Oh, Ol, woh, wol, bo, out);
}

// Round 15
// 309.593 us; speedup vs baseline: 1.0639x; 1.0070x over previous
//
#include <hip/hip_runtime.h>
#include <hip/hip_bf16.h>
#include <math.h>

// Problem constants
#define NB 8          // batch
#define NN 1024       // NQ = NK
#define ND 512        // DQ = DK = DV
#define NH 8          // heads
#define NDS 64        // head dim
#define NM 64         // NH * NB
#define LOG_A (-6.93147180559945f)     // -log(1024)
#define SQRT_V 4.75682846001088f       // 512^0.25
#define INV_SQRT_V 0.210224103813429f
#define INV_EPS 10000.0f               // 1/EPS
#define L2E  1.44269504088896f         // log2(e)
#define LN2F 0.693147180559945f
#define IEL2 14426.9504088896f         // INV_EPS * log2(e)

#define SPLIT_ELEMS ((size_t)NM * NN * NDS)   // 4,194,304 u16 (8 MB)
#define W_ELEMS     ((size_t)ND * ND)         // 262,144
#define UV_FLOATS   ((size_t)NM * NN)

typedef unsigned short u16;
typedef unsigned int   u32;
typedef __attribute__((ext_vector_type(8))) short bf16x8;   // 8 bf16 = 4 VGPR
typedef __attribute__((ext_vector_type(4))) float f32x4;

#define MFMA16(a,b,c) __builtin_amdgcn_mfma_f32_16x16x32_bf16(a,b,c,0,0,0)

__device__ __forceinline__ u16 f2bf_t(float x) {    // truncating float->bf16
  return (u16)(__float_as_uint(x) >> 16);
}
__device__ __forceinline__ float bf2f(u16 h) {
  return __uint_as_float(((u32)h) << 16);
}
__device__ __forceinline__ float fast_sqrt(float x) {   // v_sqrt_f32
  float r;
  asm("v_sqrt_f32 %0, %1" : "=v"(r) : "v"(x));
  return r;
}
__device__ __forceinline__ float fast_exp2(float x) {   // v_exp_f32 = 2^x
  float r;
  asm("v_exp_f32 %0, %1" : "=v"(r) : "v"(x));
  return r;
}
__device__ __forceinline__ float max3f(float a, float b, float c) {
  float r;
  asm("v_max3_f32 %0, %1, %2, %3" : "=v"(r) : "v"(a), "v"(b), "v"(c));
  return r;
}
// Barrier that makes LDS writes visible without draining in-flight global
// loads (neutral vs __syncthreads in round-10 A/B, kept).
__device__ __forceinline__ void soft_barrier() {
  asm volatile("s_waitcnt lgkmcnt(0)" ::: "memory");
  __builtin_amdgcn_sched_barrier(0);
  __builtin_amdgcn_s_barrier();
  __builtin_amdgcn_sched_barrier(0);
  asm volatile("" ::: "memory");
}

// ---------------------------------------------------------------------------
// K0: elementwise f32 -> bf16 hi/lo split (truncating).
// ---------------------------------------------------------------------------
__global__ __launch_bounds__(256) void k_split(
    const float* __restrict__ X, u16* __restrict__ hi, u16* __restrict__ lo)
{
  const size_t i = ((size_t)blockIdx.x * 256 + threadIdx.x) * 4;
  float4 v = *(const float4*)&X[i];
  const float* vp = (const float*)&v;
  u16 h[4], l[4];
#pragma unroll
  for (int j = 0; j < 4; ++j) {
    h[j] = f2bf_t(vp[j]);
    l[j] = f2bf_t(vp[j] - bf2f(h[j]));
  }
  uint2 ph, pl;
  ph.x = (u32)h[0] | ((u32)h[1] << 16);
  ph.y = (u32)h[2] | ((u32)h[3] << 16);
  pl.x = (u32)l[0] | ((u32)l[1] << 16);
  pl.y = (u32)l[2] | ((u32)l[3] << 16);
  *(uint2*)&hi[i] = ph;
  *(uint2*)&lo[i] = pl;
}

// ---------------------------------------------------------------------------
// K1: MFMA projection. Double-buffered LDS + soft barrier (1/K-step).
// mode 0: hi/lo split out + norms. mode 1: transposed bf16 out.
// mode 2: hi-only out + norms.
// ---------------------------------------------------------------------------
__global__ __launch_bounds__(256, 2) void k_proj_mfma(
    const u16* __restrict__ Xh, const u16* __restrict__ Xl,
    const u16* __restrict__ Wh, const u16* __restrict__ Wl,
    const float* __restrict__ bias, u16* __restrict__ oh,
    u16* __restrict__ ol, u16* __restrict__ oT,
    float* __restrict__ nrm, float scale, int mode)
{
  __shared__ __align__(16) u16 Xhs[2][64][72];
  __shared__ __align__(16) u16 Xls[2][64][72];
  __shared__ __align__(16) u16 Whs[2][64][72];
  __shared__ __align__(16) u16 Wls[2][64][72];
  const int t = threadIdx.x;
  const int r0 = blockIdx.x * 64;
  const int h  = blockIdx.y;
  const int c0 = h * 64;
  const int w = t >> 6, l = t & 63;
  const int c = l & 15, kg = l >> 4;
  const int srow = t >> 2;
  const int skoff = (t & 3) * 16;

  const u16* gxh = &Xh[(size_t)(r0 + srow) * ND + skoff];
  const u16* gxl = &Xl[(size_t)(r0 + srow) * ND + skoff];
  const u16* gwh = &Wh[(size_t)(c0 + srow) * ND + skoff];
  const u16* gwl = &Wl[(size_t)(c0 + srow) * ND + skoff];

  bf16x8 rxh0 = *(const bf16x8*)gxh, rxh1 = *(const bf16x8*)(gxh + 8);
  bf16x8 rxl0 = *(const bf16x8*)gxl, rxl1 = *(const bf16x8*)(gxl + 8);
  bf16x8 rwh0 = *(const bf16x8*)gwh, rwh1 = *(const bf16x8*)(gwh + 8);
  bf16x8 rwl0 = *(const bf16x8*)gwl, rwl1 = *(const bf16x8*)(gwl + 8);

  f32x4 acc[4];
#pragma unroll
  for (int cf = 0; cf < 4; ++cf) acc[cf] = (f32x4){0.f, 0.f, 0.f, 0.f};

  for (int kt = 0; kt < 8; ++kt) {
    const int buf = kt & 1;
    *(bf16x8*)&Xhs[buf][srow][skoff]     = rxh0;
    *(bf16x8*)&Xhs[buf][srow][skoff + 8] = rxh1;
    *(bf16x8*)&Xls[buf][srow][skoff]     = rxl0;
    *(bf16x8*)&Xls[buf][srow][skoff + 8] = rxl1;
    *(bf16x8*)&Whs[buf][srow][skoff]     = rwh0;
    *(bf16x8*)&Whs[buf][srow][skoff + 8] = rwh1;
    *(bf16x8*)&Wls[buf][srow][skoff]     = rwl0;
    *(bf16x8*)&Wls[buf][srow][skoff + 8] = rwl1;
    {
      const int nk = ((kt + 1) & 7) * 64;
      rxh0 = *(const bf16x8*)(gxh + nk); rxh1 = *(const bf16x8*)(gxh + nk + 8);
      rxl0 = *(const bf16x8*)(gxl + nk); rxl1 = *(const bf16x8*)(gxl + nk + 8);
      rwh0 = *(const bf16x8*)(gwh + nk); rwh1 = *(const bf16x8*)(gwh + nk + 8);
      rwl0 = *(const bf16x8*)(gwl + nk); rwl1 = *(const bf16x8*)(gwl + nk + 8);
    }
    soft_barrier();
#pragma unroll
    for (int ks = 0; ks < 2; ++ks) {
      bf16x8 Ah = *(const bf16x8*)&Xhs[buf][w * 16 + c][ks * 32 + kg * 8];
      bf16x8 Al = *(const bf16x8*)&Xls[buf][w * 16 + c][ks * 32 + kg * 8];
#pragma unroll
      for (int cf = 0; cf < 4; ++cf) {
        bf16x8 Bh = *(const bf16x8*)&Whs[buf][cf * 16 + c][ks * 32 + kg * 8];
        bf16x8 Bl = *(const bf16x8*)&Wls[buf][cf * 16 + c][ks * 32 + kg * 8];
        acc[cf] = MFMA16(Ah, Bh, acc[cf]);
        acc[cf] = MFMA16(Ah, Bl, acc[cf]);
        acc[cf] = MFMA16(Al, Bh, acc[cf]);
      }
    }
  }

  const int bb = r0 >> 10;
  const int n0 = r0 & 1023;
  const size_t mrow = (size_t)(h * NB + bb) * NN;
  if (mode != 1) {
    float ns[4] = {0.f, 0.f, 0.f, 0.f};
#pragma unroll
    for (int cf = 0; cf < 4; ++cf) {
      const int col = c0 + cf * 16 + c;
      const float bv = bias[col];
#pragma unroll
      for (int r = 0; r < 4; ++r) {
        float v = (acc[cf][r] + bv) * scale;
        u16 hv = f2bf_t(v);
        ns[r] = fmaf(v, v, ns[r]);
        int n = n0 + w * 16 + kg * 4 + r;
        size_t idx = (mrow + n) * NDS + cf * 16 + c;
        oh[idx] = hv;
        if (mode == 0) ol[idx] = f2bf_t(v - bf2f(hv));
      }
    }
#pragma unroll
    for (int off = 1; off <= 8; off <<= 1)
#pragma unroll
      for (int r = 0; r < 4; ++r) ns[r] += __shfl_xor(ns[r], off);
    if (c == 0) {
#pragma unroll
      for (int r = 0; r < 4; ++r)
        nrm[mrow + n0 + w * 16 + kg * 4 + r] = ns[r];
    }
  } else {
#pragma unroll
    for (int cf = 0; cf < 4; ++cf) {
      const int d = cf * 16 + c;
      const float bv = bias[c0 + d];
      u16 p0 = f2bf_t((acc[cf][0] + bv) * scale);
      u16 p1 = f2bf_t((acc[cf][1] + bv) * scale);
      u16 p2 = f2bf_t((acc[cf][2] + bv) * scale);
      u16 p3 = f2bf_t((acc[cf][3] + bv) * scale);
      uint2 p;
      p.x = (u32)p0 | ((u32)p1 << 16);
      p.y = (u32)p2 | ((u32)p3 << 16);
      *(uint2*)&oT[((size_t)(h * NB + bb) * NDS + d) * NN + n0 + w * 16 + kg * 4] = p;
    }
  }
}

// ---------------------------------------------------------------------------
// K2: MFMA LSE pass — hi-only cost; TWO j-tiles per barrier (4-plane pairs,
// 8 barriers/kernel). 512 threads / 8 waves; log2-domain flash; max3.
// ---------------------------------------------------------------------------
__global__ __launch_bounds__(512, 4) void k_lse_mfma(
    const u16* __restrict__ Ah_, const u16* __restrict__ Bh_,
    const float* __restrict__ Anrm, const float* __restrict__ Bnrm,
    const float* __restrict__ din, float* __restrict__ dout, int first)
{
  __shared__ __align__(16) float din_s[NN];   // pre-scaled by log2(e)
  __shared__ __align__(16) float y2_s[NN];
  __shared__ __align__(16) u16 Bhs[4][64][72];   // 2 pairs x 2 tiles
  const int t = threadIdx.x;
  const int Lb = blockIdx.x;                  // 512 blocks
  const int xcd = Lb & 7, slot = Lb >> 3;     // slot 0..63
  const int m = xcd + 8 * (slot >> 3);
  const int a0 = (slot & 7) * 128;

  if (first) {
    *(float2*)&din_s[t * 2] = make_float2(0.f, 0.f);
  } else {
    float2 dv = *(const float2*)&din[(size_t)m * NN + t * 2];
    dv.x *= L2E; dv.y *= L2E;
    *(float2*)&din_s[t * 2] = dv;
  }
  *(float2*)&y2_s[t * 2] = *(const float2*)&Bnrm[(size_t)m * NN + t * 2];

  const int w = t >> 6, l = t & 63;
  const int c = l & 15, kg = l >> 4;
  const int arow = a0 + w * 16;
  const size_t mbase = (size_t)m * NN * NDS;

  const u16* pah = &Ah_[mbase + (size_t)(arow + c) * NDS + kg * 8];
  bf16x8 A0h = *(const bf16x8*)pah;
  bf16x8 A1h = *(const bf16x8*)(pah + 32);

  float x2r[4];
#pragma unroll
  for (int r = 0; r < 4; ++r) x2r[r] = Anrm[(size_t)m * NN + arow + kg * 4 + r];
  float M[4], S[4];
#pragma unroll
  for (int r = 0; r < 4; ++r) { M[r] = -3.0e38f; S[r] = 0.f; }

  const int srow = t >> 3;            // 0..63
  const int skoff = (t & 7) * 8;      // one bf16x8 per thread per plane
  const u16* gh = &Bh_[mbase + (size_t)srow * NDS + skoff];
  bf16x8 r0 = *(const bf16x8*)gh;              // tile 0
  bf16x8 r1 = *(const bf16x8*)(gh + 4096);     // tile 1
  __syncthreads();   // din_s/y2_s visible

  for (int bt = 0; bt < 16; bt += 2) {
    const int p2 = (bt >> 1) & 1;     // pair index
    *(bf16x8*)&Bhs[p2 * 2 + 0][srow][skoff] = r0;
    *(bf16x8*)&Bhs[p2 * 2 + 1][srow][skoff] = r1;
    {   // prefetch tiles bt+2, bt+3 (wrap harmlessly)
      r0 = *(const bf16x8*)(gh + (size_t)((bt + 2) & 15) * 4096);
      r1 = *(const bf16x8*)(gh + (size_t)((bt + 3) & 15) * 4096);
    }
    soft_barrier();
#pragma unroll
    for (int sub = 0; sub < 2; ++sub) {
      const int b0 = (bt + sub) * 64;
      const int pl = p2 * 2 + sub;
      f32x4 acc[4];
#pragma unroll
      for (int cf = 0; cf < 4; ++cf) {
        const int bl = cf * 16 + c;
        bf16x8 B0h = *(const bf16x8*)&Bhs[pl][bl][kg * 8];
        bf16x8 B1h = *(const bf16x8*)&Bhs[pl][bl][kg * 8 + 32];
        f32x4 a = {0.f, 0.f, 0.f, 0.f};
        a = MFMA16(A0h, B0h, a);
        a = MFMA16(A1h, B1h, a);
        acc[cf] = a;
      }
      float X[4][4];
#pragma unroll
      for (int cf = 0; cf < 4; ++cf) {
        const int col = b0 + cf * 16 + c;
        const float vb2 = din_s[col];
        const float y2  = y2_s[col];
#pragma unroll
        for (int r = 0; r < 4; ++r) {
          float d2 = fmaf(-2.f, acc[cf][r], x2r[r] + y2);
          float sq = fast_sqrt(fmaxf(d2, 0.f));
          X[cf][r] = fmaf(-IEL2, sq, vb2);
        }
      }
#pragma unroll
      for (int r = 0; r < 4; ++r) {
        float m1 = max3f(X[0][r], X[1][r], X[2][r]);
        float nm = max3f(m1, X[3][r], M[r]);
        float s4 = fast_exp2(X[0][r] - nm) + fast_exp2(X[1][r] - nm)
                 + fast_exp2(X[2][r] - nm) + fast_exp2(X[3][r] - nm);
        S[r] = fmaf(S[r], fast_exp2(M[r] - nm), s4);
        M[r] = nm;
      }
    }
  }
  // combine across the 16 col-lanes
#pragma unroll
  for (int off = 1; off <= 8; off <<= 1) {
#pragma unroll
    for (int r = 0; r < 4; ++r) {
      float Mo = __shfl_xor(M[r], off);
      float So = __shfl_xor(S[r], off);
      float nm = fmaxf(M[r], Mo);
      S[r] = S[r] * fast_exp2(M[r] - nm) + So * fast_exp2(Mo - nm);
      M[r] = nm;
    }
  }
  if (c == 0) {
#pragma unroll
    for (int r = 0; r < 4; ++r)
      dout[(size_t)m * NN + arow + kg * 4 + r] =
          LOG_A - M[r] * LN2F - __logf(S[r]);
  }
}

// ---------------------------------------------------------------------------
// K3: MFMA PV pass (round-14 structure, unchanged).
// ---------------------------------------------------------------------------
__global__ __launch_bounds__(512, 4) void k_pv_mfma(
    const u16* __restrict__ qh, const u16* __restrict__ ql,
    const u16* __restrict__ kh, const u16* __restrict__ vT,
    const float* __restrict__ qn, const float* __restrict__ kn,
    const float* __restrict__ ue, const float* __restrict__ ve,
    u16* __restrict__ Oh_, u16* __restrict__ Ol_)
{
  __shared__ __align__(16) float ve_s[NN];   // pre-scaled by log2(e)
  __shared__ __align__(16) float y2_s[NN];
  __shared__ __align__(16) u16 Bhs[2][64][72];
  __shared__ __align__(16) u16 Vs[2][64][72];
  __shared__ __align__(16) u16 pT[8][16][40];   // per-wave private
  const int t = threadIdx.x;
  const int Lb = blockIdx.x;                  // 512 blocks
  const int xcd = Lb & 7, slot = Lb >> 3;     // slot 0..63
  const int m = xcd + 8 * (slot >> 3);
  const int a0 = (slot & 7) * 128;
  {
    float2 vv = *(const float2*)&ve[(size_t)m * NN + t * 2];
    vv.x *= L2E; vv.y *= L2E;
    *(float2*)&ve_s[t * 2] = vv;
  }
  *(float2*)&y2_s[t * 2] = *(const float2*)&kn[(size_t)m * NN + t * 2];

  const int w = t >> 6, l = t & 63;
  const int c = l & 15, kg = l >> 4;
  const int arow = a0 + w * 16;
  const size_t mbase = (size_t)m * NN * NDS;

  const u16* pah = &qh[mbase + (size_t)(arow + c) * NDS + kg * 8];
  bf16x8 A0h = *(const bf16x8*)pah;
  bf16x8 A1h = *(const bf16x8*)(pah + 32);

  float x2r[4], uer2[4];
#pragma unroll
  for (int r = 0; r < 4; ++r) {
    x2r[r]  = qn[(size_t)m * NN + arow + kg * 4 + r];
    uer2[r] = ue[(size_t)m * NN + arow + kg * 4 + r] * L2E;
  }
  f32x4 pacc[4];
#pragma unroll
  for (int df = 0; df < 4; ++df) pacc[df] = (f32x4){0.f, 0.f, 0.f, 0.f};

  const int srow = t >> 3;            // 0..63
  const int skoff = (t & 7) * 8;      // one bf16x8 per thread per plane
  const u16* gh = &kh[mbase + (size_t)srow * NDS + skoff];
  const u16* gv = &vT[((size_t)m * NDS + srow) * NN + skoff];
  bf16x8 rh = *(const bf16x8*)gh;
  bf16x8 rv = *(const bf16x8*)gv;
  __syncthreads();   // ve_s/y2_s visible

  for (int bt = 0; bt < 16; ++bt) {
    const int b0 = bt * 64;
    const int buf = bt & 1;
    *(bf16x8*)&Bhs[buf][srow][skoff] = rh;
    *(bf16x8*)&Vs[buf][srow][skoff]  = rv;
    {
      const int nbt = (bt + 1) & 15;
      rh = *(const bf16x8*)(gh + (size_t)nbt * 4096);
      rv = *(const bf16x8*)(gv + (size_t)nbt * 64);
    }
    soft_barrier();
    // two phases: j-half 0 (cf 0..1) then j-half 1 (cf 2..3)
#pragma unroll
    for (int ph = 0; ph < 2; ++ph) {
      f32x4 acc[2];
#pragma unroll
      for (int q = 0; q < 2; ++q) {
        const int cf = ph * 2 + q;
        const int bl = cf * 16 + c;
        bf16x8 B0h = *(const bf16x8*)&Bhs[buf][bl][kg * 8];
        bf16x8 B1h = *(const bf16x8*)&Bhs[buf][bl][kg * 8 + 32];
        f32x4 a = {0.f, 0.f, 0.f, 0.f};
        a = MFMA16(A0h, B0h, a);
        a = MFMA16(A1h, B1h, a);
        acc[q] = a;
      }
#pragma unroll
      for (int q = 0; q < 2; ++q) {
        const int cf = ph * 2 + q;
        const int col = b0 + cf * 16 + c;
        const float ve2 = ve_s[col];
        const float y2  = y2_s[col];
#pragma unroll
        for (int r = 0; r < 4; ++r) {
          float d2 = fmaf(-2.f, acc[q][r], x2r[r] + y2);
          float sq = fast_sqrt(fmaxf(d2, 0.f));
          float p  = fast_exp2(fmaf(-IEL2, sq, uer2[r] + ve2));
          pT[w][kg * 4 + r][q * 16 + c] = f2bf_t(p);
        }
      }
      bf16x8 Pa = *(const bf16x8*)&pT[w][c][kg * 8];
#pragma unroll
      for (int df = 0; df < 4; ++df) {
        bf16x8 Vb = *(const bf16x8*)&Vs[buf][df * 16 + c][ph * 32 + kg * 8];
        pacc[df] = MFMA16(Pa, Vb, pacc[df]);
      }
    }
  }
  // epilogue: O = SQRT_V * q + pacc, stored as bf16 hi/lo (truncating)
#pragma unroll
  for (int df = 0; df < 4; ++df) {
#pragma unroll
    for (int r = 0; r < 4; ++r) {
      int row = arow + kg * 4 + r;
      int d = df * 16 + c;
      size_t qi = mbase + (size_t)row * NDS + d;
      float qv = bf2f(qh[qi]) + bf2f(ql[qi]);
      float o  = fmaf(SQRT_V, qv, pacc[df][r]);
      u16 hv = f2bf_t(o);
      Oh_[qi] = hv;
      Ol_[qi] = f2bf_t(o - bf2f(hv));
    }
  }
}

// ---------------------------------------------------------------------------
// K4: MFMA output GEMM. Double-buffered LDS + soft barrier (1/K-step).
// ---------------------------------------------------------------------------
__global__ __launch_bounds__(256, 2) void k_out_mfma(
    const u16* __restrict__ Oh_, const u16* __restrict__ Ol_,
    const u16* __restrict__ Wh, const u16* __restrict__ Wl,
    const float* __restrict__ bo, float* __restrict__ out)
{
  __shared__ __align__(16) u16 Ahs[2][64][72];
  __shared__ __align__(16) u16 Als[2][64][72];
  __shared__ __align__(16) u16 Whs[2][64][72];
  __shared__ __align__(16) u16 Wls[2][64][72];
  const int t = threadIdx.x;
  const int r0 = blockIdx.x * 64;
  const int c0 = blockIdx.y * 64;
  const int bb = r0 >> 10;
  const int n0 = r0 & 1023;
  const int w = t >> 6, l = t & 63;
  const int c = l & 15, kg = l >> 4;
  const int srow = t >> 2;
  const int skoff = (t & 3) * 16;

  f32x4 acc[4];
#pragma unroll
  for (int cf = 0; cf < 4; ++cf) acc[cf] = (f32x4){0.f, 0.f, 0.f, 0.f};

  // prologue: kt = 0
  bf16x8 rah0, rah1, ral0, ral1, rwh0, rwh1, rwl0, rwl1;
  {
    const size_t ob = ((size_t)(0 * NB + bb) * NN + n0 + srow) * NDS;
    const u16* gah = &Oh_[ob + skoff];
    const u16* gal = &Ol_[ob + skoff];
    const u16* gwh = &Wh[(size_t)(c0 + srow) * ND + skoff];
    const u16* gwl = &Wl[(size_t)(c0 + srow) * ND + skoff];
    rah0 = *(const bf16x8*)gah; rah1 = *(const bf16x8*)(gah + 8);
    ral0 = *(const bf16x8*)gal; ral1 = *(const bf16x8*)(gal + 8);
    rwh0 = *(const bf16x8*)gwh; rwh1 = *(const bf16x8*)(gwh + 8);
    rwl0 = *(const bf16x8*)gwl; rwl1 = *(const bf16x8*)(gwl + 8);
  }

  for (int kt = 0; kt < 8; ++kt) {
    const int buf = kt & 1;
    *(bf16x8*)&Ahs[buf][srow][skoff]     = rah0;
    *(bf16x8*)&Ahs[buf][srow][skoff + 8] = rah1;
    *(bf16x8*)&Als[buf][srow][skoff]     = ral0;
    *(bf16x8*)&Als[buf][srow][skoff + 8] = ral1;
    *(bf16x8*)&Whs[buf][srow][skoff]     = rwh0;
    *(bf16x8*)&Whs[buf][srow][skoff + 8] = rwh1;
    *(bf16x8*)&Wls[buf][srow][skoff]     = rwl0;
    *(bf16x8*)&Wls[buf][srow][skoff + 8] = rwl1;
    {
      const int nkt = (kt + 1) & 7;
      const size_t ob = ((size_t)(nkt * NB + bb) * NN + n0 + srow) * NDS;
      const u16* gah = &Oh_[ob + skoff];
      const u16* gal = &Ol_[ob + skoff];
      const u16* gwh = &Wh[(size_t)(c0 + srow) * ND + nkt * 64 + skoff];
      const u16* gwl = &Wl[(size_t)(c0 + srow) * ND + nkt * 64 + skoff];
      rah0 = *(const bf16x8*)gah; rah1 = *(const bf16x8*)(gah + 8);
      ral0 = *(const bf16x8*)gal; ral1 = *(const bf16x8*)(gal + 8);
      rwh0 = *(const bf16x8*)gwh; rwh1 = *(const bf16x8*)(gwh + 8);
      rwl0 = *(const bf16x8*)gwl; rwl1 = *(const bf16x8*)(gwl + 8);
    }
    soft_barrier();
#pragma unroll
    for (int ks = 0; ks < 2; ++ks) {
      bf16x8 Ah = *(const bf16x8*)&Ahs[buf][w * 16 + c][ks * 32 + kg * 8];
      bf16x8 Al = *(const bf16x8*)&Als[buf][w * 16 + c][ks * 32 + kg * 8];
#pragma unroll
      for (int cf = 0; cf < 4; ++cf) {
        bf16x8 Bh = *(const bf16x8*)&Whs[buf][cf * 16 + c][ks * 32 + kg * 8];
        bf16x8 Bl = *(const bf16x8*)&Wls[buf][cf * 16 + c][ks * 32 + kg * 8];
        acc[cf] = MFMA16(Ah, Bh, acc[cf]);
        acc[cf] = MFMA16(Ah, Bl, acc[cf]);
        acc[cf] = MFMA16(Al, Bh, acc[cf]);
      }
    }
  }
#pragma unroll
  for (int cf = 0; cf < 4; ++cf) {
    const int col = c0 + cf * 16 + c;
    const int d = cf * 16 + c;
    const float bv = bo[col];
#pragma unroll
    for (int r = 0; r < 4; ++r) {
      const int n = n0 + w * 16 + kg * 4 + r;
      const size_t oi = ((size_t)(blockIdx.y * NB + bb) * NN + n) * NDS + d;
      float om = bf2f(Oh_[oi]) + bf2f(Ol_[oi]);
      out[(size_t)(r0 + w * 16 + kg * 4 + r) * ND + col] =
          om + fmaxf(acc[cf][r] + bv, 0.f);
    }
  }
}

// ---------------------------------------------------------------------------
extern "C" void kernel_launch(void* const* d_in, const int* in_sizes, int n_in,
                              void* d_out, int out_size, void* d_ws, size_t ws_size,
                              hipStream_t stream) {
  const float* Q  = (const float*)d_in[0];
  const float* K  = (const float*)d_in[1];
  const float* Wq = (const float*)d_in[2];
  const float* bq = (const float*)d_in[3];
  const float* Wk = (const float*)d_in[4];
  const float* bk = (const float*)d_in[5];
  const float* Wv = (const float*)d_in[6];
  const float* bv = (const float*)d_in[7];
  const float* Wo = (const float*)d_in[8];
  const float* bo = (const float*)d_in[9];
  float* out = (float*)d_out;

  const size_t need_bytes =
      7 * SPLIT_ELEMS * sizeof(u16) + 8 * W_ELEMS * sizeof(u16) +
      4 * UV_FLOATS * sizeof(float);
  if (ws_size < need_bytes) return;

  u16* qh = (u16*)d_ws;
  u16* ql = qh + SPLIT_ELEMS;
  u16* kh = ql + SPLIT_ELEMS;
  u16* kl = kh + SPLIT_ELEMS;   // unused (hi-only cost; K-proj uses mode 2)
  u16* vT = kl + SPLIT_ELEMS;
  u16* Oh = vT + SPLIT_ELEMS;   // phase 1-2: raw Q split; phase 3+: O hi
  u16* Ol = Oh + SPLIT_ELEMS;
  u16* wqh = Ol + SPLIT_ELEMS;
  u16* wql = wqh + W_ELEMS;
  u16* wkh = wql + W_ELEMS;
  u16* wkl = wkh + W_ELEMS;
  u16* wvh = wkl + W_ELEMS;
  u16* wvl = wvh + W_ELEMS;
  u16* woh = wvl + W_ELEMS;
  u16* wol = woh + W_ELEMS;
  float* ue = (float*)(wol + W_ELEMS);
  float* ve = ue + UV_FLOATS;
  float* qn = ve + UV_FLOATS;
  float* kn = qn + UV_FLOATS;

  u16* Qrh = Oh;                  // aliased raw input splits
  u16* Qrl = Ol;
  u16* Krh = (u16*)d_out;         // d_out fully overwritten at end
  u16* Krl = Krh + SPLIT_ELEMS;

  dim3 blk(256);
  k_split<<<dim3(4096), blk, 0, stream>>>(Q, Qrh, Qrl);
  k_split<<<dim3(4096), blk, 0, stream>>>(K, Krh, Krl);
  k_split<<<dim3(256), blk, 0, stream>>>(Wq, wqh, wql);
  k_split<<<dim3(256), blk, 0, stream>>>(Wk, wkh, wkl);
  k_split<<<dim3(256), blk, 0, stream>>>(Wv, wvh, wvl);
  k_split<<<dim3(256), blk, 0, stream>>>(Wo, woh, wol);
  k_proj_mfma<<<dim3(128, 8), blk, 0, stream>>>(Qrh, Qrl, wqh, wql, bq, qh, ql, nullptr, qn, INV_SQRT_V, 0);
  k_proj_mfma<<<dim3(128, 8), blk, 0, stream>>>(Krh, Krl, wkh, wkl, bk, kh, nullptr, nullptr, kn, INV_SQRT_V, 2);
  k_proj_mfma<<<dim3(128, 8), blk, 0, stream>>>(Krh, Krl, wvh, wvl, bv, nullptr, nullptr, vT, nullptr, 1.0f, 1);
  for (int it = 0; it < 3; ++it) {
    k_lse_mfma<<<dim3(512), dim3(512), 0, stream>>>(qh, kh, qn, kn, ve, ue, it == 0 ? 1 : 0);
    k_lse_mfma<<<dim3(512), dim3(512), 0, stream>>>(kh, qh, kn, qn, ue, ve, 0);
  }
  k_pv_mfma<<<dim3(512), dim3(512), 0, stream>>>(qh, ql, kh, vT, qn, kn, ue, ve, Oh, Ol);
  k_out_mfma<<<dim3(128, 8), blk, 0, stream>>>(Oh, Ol, woh, wol, bo, out);
}